// Round 1
// baseline (103.540 us; speedup 1.0000x reference)
//
#include <hip/hip_runtime.h>
#include <math.h>

#define NB   256
#define NHK  16
#define NHV  32
#define NDK  128
#define NDV  128
#define NQKV 8192

// One block per (b,h). 256 threads.
// Phase 1: conv+silu for q-head h/2, k-head h/2, v-head h into LDS.
// Phase 2: block-reduce sumsq(q), sumsq(k), dot(q,k); normalize in LDS.
// Phase 3: stream S0[k][v] (float4), accumulate t1 (vs k) and t2 (vs q).
// Phase 4: LDS partial-reduce over 8 k-slices, write o.
__global__ __launch_bounds__(256) void gdn_decode_kernel(
    const float* __restrict__ mixed_qkv,
    const float* __restrict__ a_in,
    const float* __restrict__ b_in,
    const float* __restrict__ conv_state,
    const float* __restrict__ conv_w,
    const float* __restrict__ dt_bias,
    const float* __restrict__ alog,
    const float* __restrict__ ssm_state,
    float* __restrict__ out)
{
    const int bh  = blockIdx.x;          // b*NHV + h
    const int b   = bh >> 5;
    const int h   = bh & 31;
    const int tid = threadIdx.x;

    __shared__ float qL[NDK], kL[NDK], vL[NDV];
    __shared__ float redq[128], redk[128], redqk[128];
    __shared__ __align__(16) float p1[8][NDV];
    __shared__ __align__(16) float p2[8][NDV];
    __shared__ float sc[2];              // eg, beta

    // ---- Phase 1: conv + silu ----
    for (int i = tid; i < 384; i += 256) {
        int seg  = i >> 7;               // 0=q, 1=k, 2=v
        int lane = i & 127;
        int head = (seg == 0) ? (h >> 1) : (seg == 1 ? 16 + (h >> 1) : 32 + h);
        int c    = head * 128 + lane;
        const float* cs = conv_state + ((size_t)b * NQKV + c) * 3;
        const float* w  = conv_w + (size_t)c * 4;
        float x   = mixed_qkv[(size_t)b * NQKV + c];
        float pre = cs[0]*w[0] + cs[1]*w[1] + cs[2]*w[2] + x*w[3];
        float y   = pre / (1.0f + expf(-pre));   // silu
        if (seg == 0)      qL[lane] = y;
        else if (seg == 1) kL[lane] = y;
        else               vL[lane] = y;
    }
    if (tid == 0) {
        float av = a_in[bh] + dt_bias[h];
        float sp = fmaxf(av, 0.0f) + log1pf(expf(-fabsf(av)));  // softplus
        float g  = -expf(alog[h]) * sp;
        sc[0] = expf(g);                                        // eg
        sc[1] = 1.0f / (1.0f + expf(-b_in[bh]));                // beta
    }
    __syncthreads();

    // ---- Phase 2: reductions (sumsq q, sumsq k, dot(q,k)) ----
    if (tid < 128) {
        float qv   = qL[tid];
        redq[tid]  = qv * qv;
        redqk[tid] = qv * kL[tid];
    } else {
        float kv        = kL[tid - 128];
        redk[tid - 128] = kv * kv;
    }
    __syncthreads();
    for (int s = 64; s > 0; s >>= 1) {
        if (tid < s) { redq[tid] += redq[tid + s]; redqk[tid] += redqk[tid + s]; }
        else if (tid >= 128 && tid < 128 + s) { redk[tid-128] += redk[tid-128+s]; }
        __syncthreads();
    }
    const float invq = (1.0f / sqrtf(redq[0] + 1e-6f)) * 0.08838834764831845f; // * DK^-0.5
    const float invk =  1.0f / sqrtf(redk[0] + 1e-6f);
    const float kq   = redqk[0] * invq * invk;   // dot(qn, kn)
    if (tid < 128) qL[tid] *= invq;
    else           kL[tid - 128] *= invk;
    __syncthreads();

    // ---- Phase 3: stream S0 ----
    const int vg = tid & 31;             // owns columns [vg*4, vg*4+4)
    const int ks = tid >> 5;             // k-slice: rows [ks*16, ks*16+16)
    const float4* Srow = (const float4*)(ssm_state + (size_t)bh * NDK * NDV);
    float4 a1 = make_float4(0.f,0.f,0.f,0.f);
    float4 a2 = make_float4(0.f,0.f,0.f,0.f);
    #pragma unroll
    for (int kk = 0; kk < 16; ++kk) {
        int k = ks * 16 + kk;
        float4 s = Srow[k * 32 + vg];
        float kw = kL[k], qw = qL[k];
        a1.x = fmaf(s.x, kw, a1.x); a1.y = fmaf(s.y, kw, a1.y);
        a1.z = fmaf(s.z, kw, a1.z); a1.w = fmaf(s.w, kw, a1.w);
        a2.x = fmaf(s.x, qw, a2.x); a2.y = fmaf(s.y, qw, a2.y);
        a2.z = fmaf(s.z, qw, a2.z); a2.w = fmaf(s.w, qw, a2.w);
    }
    *(float4*)&p1[ks][vg * 4] = a1;
    *(float4*)&p2[ks][vg * 4] = a2;
    __syncthreads();

    // ---- Phase 4: reduce 8 slices, epilogue ----
    if (tid < 128) {
        float t1 = 0.f, t2 = 0.f;
        #pragma unroll
        for (int s = 0; s < 8; ++s) { t1 += p1[s][tid]; t2 += p2[s][tid]; }
        const float eg   = sc[0];
        const float beta = sc[1];
        float dv = (vL[tid] - eg * t1) * beta;
        out[(size_t)bh * NDV + tid] = fmaf(eg, t2, kq * dv);
    }
}

extern "C" void kernel_launch(void* const* d_in, const int* in_sizes, int n_in,
                              void* d_out, int out_size, void* d_ws, size_t ws_size,
                              hipStream_t stream) {
    const float* mixed = (const float*)d_in[0];
    const float* a     = (const float*)d_in[1];
    const float* bg    = (const float*)d_in[2];
    const float* cs    = (const float*)d_in[3];
    const float* cw    = (const float*)d_in[4];
    const float* dtb   = (const float*)d_in[5];
    const float* al    = (const float*)d_in[6];
    const float* ssm   = (const float*)d_in[7];
    float* out = (float*)d_out;

    gdn_decode_kernel<<<NB * NHV, 256, 0, stream>>>(mixed, a, bg, cs, cw, dtb, al, ssm, out);
}

// Round 3
// 97.748 us; speedup vs baseline: 1.0593x; 1.0593x over previous
//
#include <hip/hip_runtime.h>
#include <math.h>

#define NB   256
#define NHK  16
#define NHV  32
#define NDK  128
#define NDV  128
#define NQKV 8192

typedef float f32x4 __attribute__((ext_vector_type(4)));

// One block per (b, hk). 256 threads. Handles the two v-heads h0=2hk, h1=2hk+1
// that share this q/k head (rep = HV/HK = 2).
// Phase 1: conv+silu for q(hk), k(16+hk), v(32+2hk), v(33+2hk) into LDS.
// Phase 2: block-reduce sumsq(q), sumsq(k), dot(q,k); normalize in LDS.
// Phase 3: stream S0 for both heads (nontemporal f32x4), accumulate
//          t1 (vs k) and t2 (vs q) per head.
// Phase 4: LDS partial-reduce over 8 k-slices per head, write o0, o1.
__global__ __launch_bounds__(256) void gdn_decode_kernel(
    const float* __restrict__ mixed_qkv,
    const float* __restrict__ a_in,
    const float* __restrict__ b_in,
    const float* __restrict__ conv_state,
    const float* __restrict__ conv_w,
    const float* __restrict__ dt_bias,
    const float* __restrict__ alog,
    const float* __restrict__ ssm_state,
    float* __restrict__ out)
{
    const int bid = blockIdx.x;          // b*NHK + hk
    const int b   = bid >> 4;
    const int hk  = bid & 15;
    const int tid = threadIdx.x;
    const int h0  = 2 * hk;              // v-head 0
    const size_t bh0 = (size_t)b * NHV + h0;

    __shared__ float qL[NDK], kL[NDK], vL[2][NDV];
    __shared__ float redq[128], redk[128], redqk[128];
    __shared__ __align__(16) float p1[8][NDV];
    __shared__ __align__(16) float p2[8][NDV];
    __shared__ float sc_eg[2], sc_beta[2];

    // ---- Phase 1: conv + silu (512 channels, 2 per thread) ----
    #pragma unroll
    for (int ii = 0; ii < 2; ++ii) {
        int i    = tid + ii * 256;
        int seg  = i >> 7;               // 0=q, 1=k, 2=v0, 3=v1
        int lane = i & 127;
        int head = (seg == 0) ? hk : (seg == 1) ? (16 + hk) : (32 + h0 + (seg - 2));
        int c    = head * 128 + lane;
        const float* cs = conv_state + ((size_t)b * NQKV + c) * 3;
        const float* w  = conv_w + (size_t)c * 4;
        float x   = mixed_qkv[(size_t)b * NQKV + c];
        float pre = cs[0]*w[0] + cs[1]*w[1] + cs[2]*w[2] + x*w[3];
        float y   = pre / (1.0f + expf(-pre));   // silu
        if (seg == 0)      qL[lane] = y;
        else if (seg == 1) kL[lane] = y;
        else               vL[seg - 2][lane] = y;
    }
    if (tid < 2) {
        size_t bh = bh0 + tid;
        int    h  = h0 + tid;
        float av = a_in[bh] + dt_bias[h];
        float sp = fmaxf(av, 0.0f) + log1pf(expf(-fabsf(av)));  // softplus
        float g  = -expf(alog[h]) * sp;
        sc_eg[tid]   = expf(g);
        sc_beta[tid] = 1.0f / (1.0f + expf(-b_in[bh]));
    }
    __syncthreads();

    // ---- Phase 2: reductions (sumsq q, sumsq k, dot(q,k)) ----
    if (tid < 128) {
        float qv   = qL[tid];
        redq[tid]  = qv * qv;
        redqk[tid] = qv * kL[tid];
    } else {
        float kv        = kL[tid - 128];
        redk[tid - 128] = kv * kv;
    }
    __syncthreads();
    for (int s = 64; s > 0; s >>= 1) {
        if (tid < s) { redq[tid] += redq[tid + s]; redqk[tid] += redqk[tid + s]; }
        else if (tid >= 128 && tid < 128 + s) { redk[tid-128] += redk[tid-128+s]; }
        __syncthreads();
    }
    const float invq = (1.0f / sqrtf(redq[0] + 1e-6f)) * 0.08838834764831845f; // * DK^-0.5
    const float invk =  1.0f / sqrtf(redk[0] + 1e-6f);
    const float kq   = redqk[0] * invq * invk;   // dot(qn, kn)
    if (tid < 128) qL[tid] *= invq;
    else           kL[tid - 128] *= invk;
    __syncthreads();

    // ---- Phase 3: stream S0 for both heads ----
    const int vg = tid & 31;             // owns columns [vg*4, vg*4+4)
    const int ks = tid >> 5;             // k-slice: rows [ks*16, ks*16+16)
    const f32x4* S0 = (const f32x4*)(ssm_state + bh0 * (NDK * NDV));
    const f32x4* S1 = S0 + (NDK * NDV / 4);
    f32x4 a1_0 = {0.f,0.f,0.f,0.f}, a2_0 = {0.f,0.f,0.f,0.f};
    f32x4 a1_1 = {0.f,0.f,0.f,0.f}, a2_1 = {0.f,0.f,0.f,0.f};
    #pragma unroll
    for (int kk = 0; kk < 16; ++kk) {
        int k = ks * 16 + kk;
        f32x4 s0 = __builtin_nontemporal_load(&S0[k * 32 + vg]);
        f32x4 s1 = __builtin_nontemporal_load(&S1[k * 32 + vg]);
        float kw = kL[k], qw = qL[k];
        a1_0 += s0 * kw;
        a2_0 += s0 * qw;
        a1_1 += s1 * kw;
        a2_1 += s1 * qw;
    }

    // ---- Phase 4: reduce 8 slices per head, epilogue ----
    // head 0
    *(f32x4*)&p1[ks][vg * 4] = a1_0;
    *(f32x4*)&p2[ks][vg * 4] = a2_0;
    __syncthreads();
    if (tid < 128) {
        float t1 = 0.f, t2 = 0.f;
        #pragma unroll
        for (int s = 0; s < 8; ++s) { t1 += p1[s][tid]; t2 += p2[s][tid]; }
        const float eg   = sc_eg[0];
        const float beta = sc_beta[0];
        float dv = (vL[0][tid] - eg * t1) * beta;
        out[bh0 * NDV + tid] = fmaf(eg, t2, kq * dv);
    }
    __syncthreads();
    // head 1
    *(f32x4*)&p1[ks][vg * 4] = a1_1;
    *(f32x4*)&p2[ks][vg * 4] = a2_1;
    __syncthreads();
    if (tid < 128) {
        float t1 = 0.f, t2 = 0.f;
        #pragma unroll
        for (int s = 0; s < 8; ++s) { t1 += p1[s][tid]; t2 += p2[s][tid]; }
        const float eg   = sc_eg[1];
        const float beta = sc_beta[1];
        float dv = (vL[1][tid] - eg * t1) * beta;
        out[(bh0 + 1) * NDV + tid] = fmaf(eg, t2, kq * dv);
    }
}

extern "C" void kernel_launch(void* const* d_in, const int* in_sizes, int n_in,
                              void* d_out, int out_size, void* d_ws, size_t ws_size,
                              hipStream_t stream) {
    const float* mixed = (const float*)d_in[0];
    const float* a     = (const float*)d_in[1];
    const float* bg    = (const float*)d_in[2];
    const float* cs    = (const float*)d_in[3];
    const float* cw    = (const float*)d_in[4];
    const float* dtb   = (const float*)d_in[5];
    const float* al    = (const float*)d_in[6];
    const float* ssm   = (const float*)d_in[7];
    float* out = (float*)d_out;

    gdn_decode_kernel<<<NB * NHK, 256, 0, stream>>>(mixed, a, bg, cs, cw, dtb, al, ssm, out);
}

// Round 4
// 88.733 us; speedup vs baseline: 1.1669x; 1.1016x over previous
//
#include <hip/hip_runtime.h>
#include <math.h>

#define NB   256
#define NHK  16
#define NHV  32
#define NDK  128
#define NDV  128
#define NQKV 8192

typedef float f32x4 __attribute__((ext_vector_type(4)));

// One block per (b, hk). 256 threads. Handles the two v-heads h0=2hk, h1=2hk+1
// that share this q/k head (rep = HV/HK = 2).
// Phase 0: PREFETCH first 8 stream iterations (both heads) into registers so
//          the HBM pipe is busy while the conv front-end runs.
// Phase 1: conv+silu for q(hk), k(16+hk), v(32+2hk), v(33+2hk) into LDS.
// Phase 2: single-wave shuffle reduction for sumsq(q), sumsq(k), dot(q,k).
// Phase 3: stream S0 for both heads (nontemporal f32x4), accumulate
//          t1 (vs k) and t2 (vs q) per head; first 8 iters use the prefetch.
// Phase 4: LDS partial-reduce over 8 k-slices per head, write o0, o1.
__global__ __launch_bounds__(256) void gdn_decode_kernel(
    const float* __restrict__ mixed_qkv,
    const float* __restrict__ a_in,
    const float* __restrict__ b_in,
    const float* __restrict__ conv_state,
    const float* __restrict__ conv_w,
    const float* __restrict__ dt_bias,
    const float* __restrict__ alog,
    const float* __restrict__ ssm_state,
    float* __restrict__ out)
{
    const int bid = blockIdx.x;          // b*NHK + hk
    const int b   = bid >> 4;
    const int hk  = bid & 15;
    const int tid = threadIdx.x;
    const int h0  = 2 * hk;              // v-head 0
    const size_t bh0 = (size_t)b * NHV + h0;

    __shared__ float qL[NDK], kL[NDK], vL[2][NDV];
    __shared__ float red[3];             // sumsq(q), dot(q,k), sumsq(k)
    __shared__ __align__(16) float p1[8][NDV];
    __shared__ __align__(16) float p2[8][NDV];
    __shared__ float sc_eg[2], sc_beta[2];

    // ---- Phase 0: prefetch first 8 stream iterations ----
    const int vg = tid & 31;             // owns columns [vg*4, vg*4+4)
    const int ks = tid >> 5;             // k-slice: rows [ks*16, ks*16+16)
    const f32x4* S0 = (const f32x4*)(ssm_state + bh0 * (NDK * NDV));
    const f32x4* S1 = S0 + (NDK * NDV / 4);
    constexpr int P = 8;
    f32x4 buf0[P], buf1[P];
    #pragma unroll
    for (int kk = 0; kk < P; ++kk) {
        int k = ks * 16 + kk;
        buf0[kk] = __builtin_nontemporal_load(&S0[k * 32 + vg]);
        buf1[kk] = __builtin_nontemporal_load(&S1[k * 32 + vg]);
    }

    // ---- Phase 1: conv + silu (512 channels, 2 per thread) ----
    #pragma unroll
    for (int ii = 0; ii < 2; ++ii) {
        int i    = tid + ii * 256;
        int seg  = i >> 7;               // 0=q, 1=k, 2=v0, 3=v1
        int lane = i & 127;
        int head = (seg == 0) ? hk : (seg == 1) ? (16 + hk) : (32 + h0 + (seg - 2));
        int c    = head * 128 + lane;
        const float* cs = conv_state + ((size_t)b * NQKV + c) * 3;
        const float* w  = conv_w + (size_t)c * 4;
        float x   = mixed_qkv[(size_t)b * NQKV + c];
        float pre = cs[0]*w[0] + cs[1]*w[1] + cs[2]*w[2] + x*w[3];
        float y   = pre / (1.0f + expf(-pre));   // silu
        if (seg == 0)      qL[lane] = y;
        else if (seg == 1) kL[lane] = y;
        else               vL[seg - 2][lane] = y;
    }
    if (tid >= 64 && tid < 66) {         // wave 1 does scalars (wave 0 reduces)
        int    t  = tid - 64;
        size_t bh = bh0 + t;
        int    h  = h0 + t;
        float av = a_in[bh] + dt_bias[h];
        float sp = fmaxf(av, 0.0f) + log1pf(expf(-fabsf(av)));  // softplus
        float g  = -expf(alog[h]) * sp;
        sc_eg[t]   = expf(g);
        sc_beta[t] = 1.0f / (1.0f + expf(-b_in[bh]));
    }
    __syncthreads();

    // ---- Phase 2: single-wave shuffle reduction ----
    if (tid < 64) {
        float q0 = qL[tid], q1 = qL[tid + 64];
        float k0 = kL[tid], k1 = kL[tid + 64];
        float sq  = q0*q0 + q1*q1;
        float sqk = q0*k0 + q1*k1;
        float sk  = k0*k0 + k1*k1;
        #pragma unroll
        for (int off = 32; off > 0; off >>= 1) {
            sq  += __shfl_down(sq,  off);
            sqk += __shfl_down(sqk, off);
            sk  += __shfl_down(sk,  off);
        }
        if (tid == 0) { red[0] = sq; red[1] = sqk; red[2] = sk; }
    }
    __syncthreads();
    const float invq = (1.0f / sqrtf(red[0] + 1e-6f)) * 0.08838834764831845f; // * DK^-0.5
    const float invk =  1.0f / sqrtf(red[2] + 1e-6f);
    const float kq   = red[1] * invq * invk;     // dot(qn, kn)
    if (tid < 128) qL[tid] *= invq;
    else           kL[tid - 128] *= invk;
    __syncthreads();

    // ---- Phase 3: stream S0 for both heads ----
    f32x4 a1_0 = {0.f,0.f,0.f,0.f}, a2_0 = {0.f,0.f,0.f,0.f};
    f32x4 a1_1 = {0.f,0.f,0.f,0.f}, a2_1 = {0.f,0.f,0.f,0.f};
    #pragma unroll
    for (int kk = 0; kk < 16; ++kk) {
        int k = ks * 16 + kk;
        f32x4 s0 = (kk < P) ? buf0[kk] : __builtin_nontemporal_load(&S0[k * 32 + vg]);
        f32x4 s1 = (kk < P) ? buf1[kk] : __builtin_nontemporal_load(&S1[k * 32 + vg]);
        float kw = kL[k], qw = qL[k];
        a1_0 += s0 * kw;
        a2_0 += s0 * qw;
        a1_1 += s1 * kw;
        a2_1 += s1 * qw;
    }

    // ---- Phase 4: reduce 8 slices per head, epilogue ----
    // head 0
    *(f32x4*)&p1[ks][vg * 4] = a1_0;
    *(f32x4*)&p2[ks][vg * 4] = a2_0;
    __syncthreads();
    if (tid < 128) {
        float t1 = 0.f, t2 = 0.f;
        #pragma unroll
        for (int s = 0; s < 8; ++s) { t1 += p1[s][tid]; t2 += p2[s][tid]; }
        const float eg   = sc_eg[0];
        const float beta = sc_beta[0];
        float dv = (vL[0][tid] - eg * t1) * beta;
        out[bh0 * NDV + tid] = fmaf(eg, t2, kq * dv);
    }
    __syncthreads();
    // head 1
    *(f32x4*)&p1[ks][vg * 4] = a1_1;
    *(f32x4*)&p2[ks][vg * 4] = a2_1;
    __syncthreads();
    if (tid < 128) {
        float t1 = 0.f, t2 = 0.f;
        #pragma unroll
        for (int s = 0; s < 8; ++s) { t1 += p1[s][tid]; t2 += p2[s][tid]; }
        const float eg   = sc_eg[1];
        const float beta = sc_beta[1];
        float dv = (vL[1][tid] - eg * t1) * beta;
        out[(bh0 + 1) * NDV + tid] = fmaf(eg, t2, kq * dv);
    }
}

extern "C" void kernel_launch(void* const* d_in, const int* in_sizes, int n_in,
                              void* d_out, int out_size, void* d_ws, size_t ws_size,
                              hipStream_t stream) {
    const float* mixed = (const float*)d_in[0];
    const float* a     = (const float*)d_in[1];
    const float* bg    = (const float*)d_in[2];
    const float* cs    = (const float*)d_in[3];
    const float* cw    = (const float*)d_in[4];
    const float* dtb   = (const float*)d_in[5];
    const float* al    = (const float*)d_in[6];
    const float* ssm   = (const float*)d_in[7];
    float* out = (float*)d_out;

    gdn_decode_kernel<<<NB * NHK, 256, 0, stream>>>(mixed, a, bg, cs, cw, dtb, al, ssm, out);
}